// Round 6
// baseline (591.007 us; speedup 1.0000x reference)
//
#include <hip/hip_runtime.h>

// CARAFE: x [4,256,64,64] f32, kernel [4,25,128,128] f32 -> out [4,256,128,128] f32
// out[b,c,2h+p,2w+q] = sum_{ki,kj} x[b,c,h+ki-2,w+kj-2] * kern[b,ki*5+kj,2h+p,2w+q]
//
// Round 5: zero LDS, zero barriers (R3 data: 74.75KB LDS -> 2 blk/CU, 20% occ,
// latency-bound at 80us, HBM 13%, VALU 22%). Rely on L1/L2 for the 25x tap reuse
// of x and weight broadcast. XCD-chunked bid swizzle keeps each XCD's working set
// (~2.4MB x slice + 0.8MB kern slice) inside its private 4MB L2. Non-temporal
// stores keep the 64MB write-once output stream from evicting it.
// (R4 fix: __builtin_nontemporal_store needs a clang ext_vector, not HIP float2.)

typedef float v2f __attribute__((ext_vector_type(2)));

__global__ __launch_bounds__(256, 4)
void carafe_kernel(const float* __restrict__ x,
                   const float* __restrict__ kern,
                   float* __restrict__ out) {
    // XCD-chunked swizzle: HW round-robins blockIdx%8 across XCDs; remap so each
    // XCD gets a contiguous range of logical ids. 2048 % 8 == 0 -> bijective.
    const int raw = blockIdx.x;
    const int l   = (raw & 7) * 256 + (raw >> 3);

    const int cc = l & 7;          // channel chunk (8 x 32 ch)
    const int h  = (l >> 3) & 63;  // input row
    const int b  = l >> 9;         // batch
    const int tid = threadIdx.x;
    const int w  = tid & 63;       // input column (lane dim -> coalesced)
    const int cg = tid >> 6;       // 8-channel group within chunk
    const int c0 = cc * 32 + cg * 8;

    const float* xb = x + (size_t)(b * 256 + c0) * (64 * 64);
    const float* kb = kern + ((size_t)(b * 25) * 128 + 2 * h) * 128 + 2 * w;

    float acc[4][8];               // [p*2+q][ch]
#pragma unroll
    for (int i = 0; i < 4; ++i)
#pragma unroll
        for (int j = 0; j < 8; ++j) acc[i][j] = 0.0f;

#pragma unroll
    for (int ki = 0; ki < 5; ++ki) {
        const int gr  = h + ki - 2;
        const bool rok = (unsigned)gr < 64u;     // wave-uniform
#pragma unroll
        for (int kj = 0; kj < 5; ++kj) {
            const int k  = ki * 5 + kj;
            const int gc = w + kj - 2;
            const bool ok = rok && ((unsigned)gc < 64u);
            // weights: lane stride 8B -> one 512B segment per load pair; L1-broadcast
            // across the 4 ch-group waves of this block.
            const v2f w0 = *(const v2f*)(kb + (size_t)k * (128 * 128));
            const v2f w1 = *(const v2f*)(kb + (size_t)k * (128 * 128) + 128);
#pragma unroll
            for (int ch = 0; ch < 8; ++ch) {
                const float xv = ok ? xb[(size_t)ch * (64 * 64) + gr * 64 + gc] : 0.0f;
                acc[0][ch] += w0.x * xv;
                acc[1][ch] += w0.y * xv;
                acc[2][ch] += w1.x * xv;
                acc[3][ch] += w1.y * xv;
            }
        }
    }

    // out: v2f per (ch,p) -> each wave covers a contiguous 512B segment.
    // Non-temporal: output is write-once, keep it out of the XCD L2 working set.
    float* ob = out + ((size_t)(b * 256 + c0) * 128 + 2 * h) * 128 + 2 * w;
#pragma unroll
    for (int ch = 0; ch < 8; ++ch) {
        v2f v0; v0.x = acc[0][ch]; v0.y = acc[1][ch];
        v2f v1; v1.x = acc[2][ch]; v1.y = acc[3][ch];
        __builtin_nontemporal_store(v0, (v2f*)(ob + (size_t)ch * (128 * 128)));
        __builtin_nontemporal_store(v1, (v2f*)(ob + (size_t)ch * (128 * 128) + 128));
    }
}

extern "C" void kernel_launch(void* const* d_in, const int* in_sizes, int n_in,
                              void* d_out, int out_size, void* d_ws, size_t ws_size,
                              hipStream_t stream) {
    const float* x    = (const float*)d_in[0];
    const float* kern = (const float*)d_in[1];
    float* out        = (float*)d_out;
    // grid: b(4) * h(64) * cc(8) = 2048 blocks of 256 threads
    carafe_kernel<<<dim3(2048), dim3(256), 0, stream>>>(x, kern, out);
}

// Round 7
// 30.840 us; speedup vs baseline: 19.1634x; 19.1634x over previous
//
#include <hip/hip_runtime.h>

// CARAFE: x [4,256,64,64] f32, kernel [4,25,128,128] f32 -> out [4,256,128,128] f32
// out[b,c,2h+p,2w+q] = sum_{ki,kj} x[b,c,h+ki-2,w+kj-2] * kern[b,ki*5+kj,2h+p,2w+q]
//
// R7: register-tiled. R6's NT 8B stores caused 17x HBM write amplification
// (ECC RMW): WRITE 1.1GB, FETCH 750MB, 591us. R3's LDS-everything was
// latency/instruction-bound (80us, 20% occ). Here: weights in LDS (25.6KB only,
// XOR-swizzled vs 4-way conflicts), x via 3 aligned float4 global loads per
// (ch,row) serving all 25 taps from registers, 4 cols x 4 ch x 4 subpix = 64
// outputs/thread, plain float4 stores (L2 write-combines). HBM floor ~14us.

typedef float v4 __attribute__((ext_vector_type(4)));

__global__ __launch_bounds__(256, 2)
void carafe_kernel(const float* __restrict__ x,
                   const float* __restrict__ kern,
                   float* __restrict__ out) {
    // wt[k][p][ow]: 25*2*128 floats, 16B-cell XOR swizzle: fidx ^= ((fidx>>6)&1)<<2
    __shared__ __align__(16) float wt[25 * 256];

    // XCD-chunked swizzle: 1024 blocks, 128 per XCD -> contiguous logical range.
    const int raw = blockIdx.x;
    const int l   = (raw & 7) * 128 + (raw >> 3);
    const int cc  = l & 3;           // 64-channel chunk
    const int h   = (l >> 2) & 63;   // input row
    const int b   = l >> 8;          // batch
    const int tid = threadIdx.x;
    const int t   = tid & 15;        // col group: input cols 4t..4t+3
    const int g   = tid >> 4;        // ch group: 4 channels
    const int c0  = cc * 64 + g * 4;

    // ---- stage weights for output rows {2h,2h+1}: coalesced, swizzled write ----
    const float* kbase = kern + (size_t)b * 25 * 16384 + (size_t)(2 * h) * 128;
    const int stid = tid ^ (((tid >> 6) & 1) << 2);   // swizzled slot within 256
#pragma unroll
    for (int i = 0; i < 25; ++i)
        wt[i * 256 + stid] = kbase[(size_t)i * 16384 + tid];
    __syncthreads();

    float acc[4][4][2][2] = {};      // [ch][cj][p][q]

    const float* xb  = x + (size_t)(b * 256 + c0) * 4096;
    const int    wsw = (t >= 8) ? 4 : 0;   // read-side swizzle (bit6 of f <=> t>=8)

#pragma unroll
    for (int ki = 0; ki < 5; ++ki) {
        const int gr = h + ki - 2;
        if ((unsigned)gr >= 64u) continue;        // block-uniform: zero-pad rows

        // x window per ch: cols 4t-2 .. 4t+6 (9 floats) via 3 aligned float4s.
        float xw[4][9];
#pragma unroll
        for (int ch = 0; ch < 4; ++ch) {
            const float* rowp = xb + (size_t)ch * 4096 + gr * 64;
            const v4 A  = *(const v4*)(rowp + (t ? 4 * t - 4 : 0));        // cols 4t-4..4t-1
            const v4 Bv = *(const v4*)(rowp + 4 * t);                      // cols 4t..4t+3
            const v4 D  = *(const v4*)(rowp + (t < 15 ? 4 * t + 4 : 60));  // cols 4t+4..4t+7
            xw[ch][0] = t ? A.z : 0.0f;            // col 4t-2
            xw[ch][1] = t ? A.w : 0.0f;            // col 4t-1
            xw[ch][2] = Bv.x; xw[ch][3] = Bv.y; xw[ch][4] = Bv.z; xw[ch][5] = Bv.w;
            xw[ch][6] = (t < 15) ? D.x : 0.0f;     // col 4t+4
            xw[ch][7] = (t < 15) ? D.y : 0.0f;     // col 4t+5
            xw[ch][8] = (t < 15) ? D.z : 0.0f;     // col 4t+6
        }

#pragma unroll
        for (int kj = 0; kj < 5; ++kj) {
            const int k  = ki * 5 + kj;
            const int f0 = k * 256 + 8 * t;        // p=0, ow 8t (orig index, bit2=0)
            const int f1 = f0 + 128;               // p=1
            const v4 w0a = *(const v4*)&wt[f0 ^ wsw];
            const v4 w0b = *(const v4*)&wt[(f0 + 4) ^ wsw];
            const v4 w1a = *(const v4*)&wt[f1 ^ wsw];
            const v4 w1b = *(const v4*)&wt[(f1 + 4) ^ wsw];
            const float w0v[8] = {w0a.x, w0a.y, w0a.z, w0a.w, w0b.x, w0b.y, w0b.z, w0b.w};
            const float w1v[8] = {w1a.x, w1a.y, w1a.z, w1a.w, w1b.x, w1b.y, w1b.z, w1b.w};
#pragma unroll
            for (int ch = 0; ch < 4; ++ch) {
#pragma unroll
                for (int cj = 0; cj < 4; ++cj) {
                    const float xv = xw[ch][cj + kj];
                    acc[ch][cj][0][0] += w0v[2 * cj]     * xv;
                    acc[ch][cj][0][1] += w0v[2 * cj + 1] * xv;
                    acc[ch][cj][1][0] += w1v[2 * cj]     * xv;
                    acc[ch][cj][1][1] += w1v[2 * cj + 1] * xv;
                }
            }
        }
    }

    // ---- stores: out cols 8t+2cj+q; two float4 per (ch,p); plain (L2 merges) ----
#pragma unroll
    for (int ch = 0; ch < 4; ++ch) {
        float* ob = out + ((size_t)(b * 256 + c0 + ch) * 128 + 2 * h) * 128 + 8 * t;
#pragma unroll
        for (int p = 0; p < 2; ++p) {
            v4 s0, s1;
            s0.x = acc[ch][0][p][0]; s0.y = acc[ch][0][p][1];
            s0.z = acc[ch][1][p][0]; s0.w = acc[ch][1][p][1];
            s1.x = acc[ch][2][p][0]; s1.y = acc[ch][2][p][1];
            s1.z = acc[ch][3][p][0]; s1.w = acc[ch][3][p][1];
            *(v4*)(ob + p * 128)     = s0;
            *(v4*)(ob + p * 128 + 4) = s1;
        }
    }
}

extern "C" void kernel_launch(void* const* d_in, const int* in_sizes, int n_in,
                              void* d_out, int out_size, void* d_ws, size_t ws_size,
                              hipStream_t stream) {
    const float* x    = (const float*)d_in[0];
    const float* kern = (const float*)d_in[1];
    float* out        = (float*)d_out;
    // grid: b(4) * h(64) * cc(4) = 1024 blocks of 256 threads
    carafe_kernel<<<dim3(1024), dim3(256), 0, stream>>>(x, kern, out);
}

// Round 8
// 29.274 us; speedup vs baseline: 20.1891x; 1.0535x over previous
//
#include <hip/hip_runtime.h>

// CARAFE: x [4,256,64,64] f32, kernel [4,25,128,128] f32 -> out [4,256,128,128] f32
// out[b,c,2h+p,2w+q] = sum_{ki,kj} x[b,c,h+ki-2,w+kj-2] * kern[b,ki*5+kj,2h+p,2w+q]
//
// R8: smaller per-thread tile for occupancy-driven overlap. R7 (4col x 4ch,
// VGPR~150, 2-3 waves/SIMD) = 30.8us: LDS/L1/VALU/store phases barely overlap.
// Here 2col x 4ch: acc 32 + xw 24 -> ~90 VGPR -> ~5 waves/SIMD; weight LDS
// halves to 2 ds_read_b128 per tap (8 floats serve 32 FMA). Plain v4 stores
// (R6 lesson: NT sub-line stores = 17x ECC-RMW amplification). HBM floor ~14us.

typedef float v2 __attribute__((ext_vector_type(2)));
typedef float v4 __attribute__((ext_vector_type(4)));

__global__ __launch_bounds__(256, 4)
void carafe_kernel(const float* __restrict__ x,
                   const float* __restrict__ kern,
                   float* __restrict__ out) {
    __shared__ __align__(16) float wt[25 * 256];   // [k][p][ow0..127] for rows {2h,2h+1}

    // XCD-chunked swizzle: 2048 blocks, 256 per XCD.
    const int raw = blockIdx.x;
    const int l   = (raw & 7) * 256 + (raw >> 3);
    const int cc  = l & 7;           // 32-channel chunk
    const int h   = (l >> 3) & 63;   // input row
    const int b   = l >> 9;          // batch
    const int tid = threadIdx.x;
    const int t   = tid & 31;        // col group: input cols 2t, 2t+1
    const int g   = tid >> 5;        // ch group: 4 channels
    const int c0  = cc * 32 + g * 4;

    // ---- stage weights (25.6KB), coalesced ----
    const float* kbase = kern + (size_t)b * 25 * 16384 + (size_t)(2 * h) * 128;
#pragma unroll
    for (int i = 0; i < 25; ++i)
        wt[i * 256 + tid] = kbase[(size_t)i * 16384 + tid];
    __syncthreads();

    float acc[4][2][2][2] = {};      // [ch][cj][p][q]
    const float* xb = x + (size_t)(b * 256 + c0) * 4096;

#pragma unroll
    for (int ki = 0; ki < 5; ++ki) {
        const int gr = h + ki - 2;
        if ((unsigned)gr >= 64u) continue;     // block-uniform zero rows

        // x window per ch: cols 2t-2 .. 2t+3 via 3 aligned v2 loads
        float xw[4][6];
#pragma unroll
        for (int ch = 0; ch < 4; ++ch) {
            const float* rowp = xb + (size_t)ch * 4096 + gr * 64;
            const v2 A = *(const v2*)(rowp + (t ? 2 * t - 2 : 0));
            const v2 B = *(const v2*)(rowp + 2 * t);
            const v2 C = *(const v2*)(rowp + (t < 31 ? 2 * t + 2 : 60));
            xw[ch][0] = t ? A.x : 0.0f;            // col 2t-2
            xw[ch][1] = t ? A.y : 0.0f;            // col 2t-1
            xw[ch][2] = B.x;  xw[ch][3] = B.y;     // cols 2t, 2t+1
            xw[ch][4] = (t < 31) ? C.x : 0.0f;     // col 2t+2
            xw[ch][5] = (t < 31) ? C.y : 0.0f;     // col 2t+3
        }

#pragma unroll
        for (int kj = 0; kj < 5; ++kj) {
            const int k = ki * 5 + kj;
            const v4 w0 = *(const v4*)&wt[k * 256 + 4 * t];        // p=0, ow 4t..4t+3
            const v4 w1 = *(const v4*)&wt[k * 256 + 128 + 4 * t];  // p=1
#pragma unroll
            for (int ch = 0; ch < 4; ++ch) {
#pragma unroll
                for (int cj = 0; cj < 2; ++cj) {
                    const float xv = xw[ch][cj + kj];
                    acc[ch][cj][0][0] += w0[2 * cj]     * xv;
                    acc[ch][cj][0][1] += w0[2 * cj + 1] * xv;
                    acc[ch][cj][1][0] += w1[2 * cj]     * xv;
                    acc[ch][cj][1][1] += w1[2 * cj + 1] * xv;
                }
            }
        }
    }

    // ---- stores: 1 v4 per (ch,p); lanes t=0..31 cover a contiguous 512B row ----
#pragma unroll
    for (int ch = 0; ch < 4; ++ch) {
        float* ob = out + ((size_t)(b * 256 + c0 + ch) * 128 + 2 * h) * 128 + 4 * t;
#pragma unroll
        for (int p = 0; p < 2; ++p) {
            v4 s;
            s.x = acc[ch][0][p][0]; s.y = acc[ch][0][p][1];
            s.z = acc[ch][1][p][0]; s.w = acc[ch][1][p][1];
            *(v4*)(ob + p * 128) = s;
        }
    }
}

extern "C" void kernel_launch(void* const* d_in, const int* in_sizes, int n_in,
                              void* d_out, int out_size, void* d_ws, size_t ws_size,
                              hipStream_t stream) {
    const float* x    = (const float*)d_in[0];
    const float* kern = (const float*)d_in[1];
    float* out        = (float*)d_out;
    // grid: b(4) * h(64) * cc(8) = 2048 blocks of 256 threads
    carafe_kernel<<<dim3(2048), dim3(256), 0, stream>>>(x, kern, out);
}